// Round 9
// baseline (166.891 us; speedup 1.0000x reference)
//
#include <hip/hip_runtime.h>

#define EPS_W 1e-6f
#define IPB 128

__device__ __forceinline__ float fast_rsq(float x) { return __builtin_amdgcn_rsqf(x); }
__device__ __forceinline__ float fast_rcp(float x) { return __builtin_amdgcn_rcpf(x); }

// ---------------------------------------------------------------------------
// Horn-quaternion solve via 5-sweep cyclic Jacobi on N (4x4).
// IDENTICAL to round-7/8 verified version (absmax 0.0039).
// S[16] = { sw, Sa0..2, Sb0..2, M00,M01,M02,M10,M11,M12,M20,M21,M22 }
// ---------------------------------------------------------------------------
__device__ __forceinline__ void solve16(const float S[16], float R[9], float t[3])
{
    const float sw  = S[0];
    const float Sa0 = S[1], Sa1 = S[2], Sa2 = S[3];
    const float Sb0 = S[4], Sb1 = S[5], Sb2 = S[6];

    const float inv = fast_rcp(sw + EPS_W);
    const float cA0 = Sa0*inv, cA1 = Sa1*inv, cA2 = Sa2*inv;
    const float cB0 = Sb0*inv, cB1 = Sb1*inv, cB2 = Sb2*inv;

    float H[3][3];
    H[0][0] = S[7]  - cA0*Sb0 - Sa0*cB0 + sw*cA0*cB0;
    H[0][1] = S[8]  - cA0*Sb1 - Sa0*cB1 + sw*cA0*cB1;
    H[0][2] = S[9]  - cA0*Sb2 - Sa0*cB2 + sw*cA0*cB2;
    H[1][0] = S[10] - cA1*Sb0 - Sa1*cB0 + sw*cA1*cB0;
    H[1][1] = S[11] - cA1*Sb1 - Sa1*cB1 + sw*cA1*cB1;
    H[1][2] = S[12] - cA1*Sb2 - Sa1*cB2 + sw*cA1*cB2;
    H[2][0] = S[13] - cA2*Sb0 - Sa2*cB0 + sw*cA2*cB0;
    H[2][1] = S[14] - cA2*Sb1 - Sa2*cB1 + sw*cA2*cB1;
    H[2][2] = S[15] - cA2*Sb2 - Sa2*cB2 + sw*cA2*cB2;

    const float Sxx=H[0][0], Sxy=H[0][1], Sxz=H[0][2];
    const float Syx=H[1][0], Syy=H[1][1], Syz=H[1][2];
    const float Szx=H[2][0], Szy=H[2][1], Szz=H[2][2];

    float Nm[4][4];
    Nm[0][0] =  Sxx+Syy+Szz; Nm[0][1] = Syz-Szy;      Nm[0][2] = Szx-Sxz;      Nm[0][3] = Sxy-Syx;
    Nm[1][0] =  Nm[0][1];    Nm[1][1] = Sxx-Syy-Szz;  Nm[1][2] = Sxy+Syx;      Nm[1][3] = Szx+Sxz;
    Nm[2][0] =  Nm[0][2];    Nm[2][1] = Nm[1][2];     Nm[2][2] = -Sxx+Syy-Szz; Nm[2][3] = Syz+Szy;
    Nm[3][0] =  Nm[0][3];    Nm[3][1] = Nm[1][3];     Nm[3][2] = Nm[2][3];     Nm[3][3] = -Sxx-Syy+Szz;

    float Vv[4][4] = {{1.f,0.f,0.f,0.f},{0.f,1.f,0.f,0.f},{0.f,0.f,1.f,0.f},{0.f,0.f,0.f,1.f}};

    for (int sweep = 0; sweep < 5; ++sweep) {
        #pragma unroll
        for (int pair = 0; pair < 6; ++pair) {
            constexpr int PP[6] = {0,0,0,1,1,2};
            constexpr int QQ[6] = {1,2,3,2,3,3};
            const int p = PP[pair], q = QQ[pair];
            float d  = Nm[p][p] - Nm[q][q];
            float o  = Nm[p][q];
            float r2 = d*d + 4.f*o*o;
            bool tiny = r2 < 1e-30f;
            float rinv = fast_rsq(tiny ? 1.f : r2);
            float hh = 0.5f + 0.5f * fabsf(d) * rinv;
            float ci = fast_rsq(hh);
            float c  = hh * ci;
            float s  = (d < 0.f ? o : -o) * rinv * ci;
            c = tiny ? 1.f : c;
            s = tiny ? 0.f : s;
            #pragma unroll
            for (int k = 0; k < 4; ++k) {
                float akp = Nm[k][p], akq = Nm[k][q];
                Nm[k][p] = c*akp - s*akq;
                Nm[k][q] = s*akp + c*akq;
            }
            #pragma unroll
            for (int k = 0; k < 4; ++k) {
                float apk = Nm[p][k], aqk = Nm[q][k];
                Nm[p][k] = c*apk - s*aqk;
                Nm[q][k] = s*apk + c*aqk;
            }
            #pragma unroll
            for (int k = 0; k < 4; ++k) {
                float vkp = Vv[k][p], vkq = Vv[k][q];
                Vv[k][p] = c*vkp - s*vkq;
                Vv[k][q] = s*vkp + c*vkq;
            }
        }
    }

    float q0=Vv[0][0], q1=Vv[1][0], q2=Vv[2][0], q3=Vv[3][0];
    float best = Nm[0][0];
    #pragma unroll
    for (int m = 1; m < 4; ++m) {
        bool bt = Nm[m][m] > best;
        best = bt ? Nm[m][m] : best;
        q0 = bt ? Vv[0][m] : q0;
        q1 = bt ? Vv[1][m] : q1;
        q2 = bt ? Vv[2][m] : q2;
        q3 = bt ? Vv[3][m] : q3;
    }
    float qn = fast_rsq(q0*q0 + q1*q1 + q2*q2 + q3*q3);
    q0*=qn; q1*=qn; q2*=qn; q3*=qn;

    float R00 = q0*q0+q1*q1-q2*q2-q3*q3;
    float R01 = 2.f*(q1*q2 - q0*q3);
    float R02 = 2.f*(q1*q3 + q0*q2);
    float R10 = 2.f*(q1*q2 + q0*q3);
    float R11 = q0*q0-q1*q1+q2*q2-q3*q3;
    float R12 = 2.f*(q2*q3 - q0*q1);
    float R20 = 2.f*(q1*q3 - q0*q2);
    float R21 = 2.f*(q2*q3 + q0*q1);
    float R22 = q0*q0-q1*q1-q2*q2+q3*q3;

    float trRH  = R00*Sxx+R01*Syx+R02*Szx
                + R10*Sxy+R11*Syy+R12*Szy
                + R20*Sxz+R21*Syz+R22*Szz;
    float trRtH = R00*Sxx+R01*Sxy+R02*Sxz
                + R10*Syx+R11*Syy+R12*Syz
                + R20*Szx+R21*Szy+R22*Szz;
    if (trRtH > trRH) {
        float tt;
        tt = R01; R01 = R10; R10 = tt;
        tt = R02; R02 = R20; R20 = tt;
        tt = R12; R12 = R21; R21 = tt;
    }

    R[0]=R00; R[1]=R01; R[2]=R02;
    R[3]=R10; R[4]=R11; R[5]=R12;
    R[6]=R20; R[7]=R21; R[8]=R22;
    t[0] = cB0 - (R00*cA0 + R01*cA1 + R02*cA2);
    t[1] = cB1 - (R10*cA0 + R11*cA1 + R12*cA2);
    t[2] = cB2 - (R20*cA0 + R21*cA1 + R22*cA2);
}

// ---------------------------------------------------------------------------
// v9: 128 items / 256 threads, ONE 32KB LDS buffer reused W->A->B.
//  - staging: coalesced float4 loads (16 lines/instr, L2-efficient),
//    ds_write_b128 into XOR-swizzled chunks (c ^ (i&15)) of 256B rows.
//  - compute: ALL 256 threads accumulate (2 threads/item, verified math),
//    reading per-thread float2s with the matching swizzle (<=4-way banks).
//  - pair-combine via shfl_xor, sums through LDS (stride 17, conflict-free),
//    solve on threads 0..127 (waves 2,3 retire early), 64B/thread stores.
// ---------------------------------------------------------------------------
__global__ __launch_bounds__(256, 4) void kabsch_swz20_kernel(
    const float* __restrict__ A, const float* __restrict__ B,
    const float* __restrict__ W, float* __restrict__ Out, int bs)
{
    __shared__ float sbuf[8192];          // 32 KB, reused 3x
    float4* s4 = reinterpret_cast<float4*>(sbuf);
    float2* s2 = reinterpret_cast<float2*>(sbuf);

    const int tid  = threadIdx.x;
    const int base = blockIdx.x * IPB;
    int itemcnt = bs - base;
    if (itemcnt > IPB) itemcnt = IPB;

    const int i = tid >> 1;               // item-in-block, 0..127
    const int h = tid & 1;                // half (points 0..9 / 10..19)
    const bool act = (i < itemcnt);

    // ---- W: stage (96B rows, no swizzle) + read 5 float2 ----
    const float4* Wg = reinterpret_cast<const float4*>(W) + (size_t)base * 5;
    const int nW4 = itemcnt * 5;
    for (int g = tid; g < nW4; g += 256) {
        const int it = g / 5, c = g - it * 5;
        s4[it * 6 + c] = Wg[g];
    }
    __syncthreads();
    float wv[10];
    if (act) {
        #pragma unroll
        for (int g = 0; g < 5; ++g) {
            float2 v = s2[i * 12 + 5 * h + g];
            wv[2*g] = v.x; wv[2*g+1] = v.y;
        }
    }
    __syncthreads();

    // ---- A: stage swizzled (256B rows, chunk c -> c ^ (i&15)) + read ----
    const float4* Ag = reinterpret_cast<const float4*>(A) + (size_t)base * 15;
    const int n4 = itemcnt * 15;
    for (int g = tid; g < n4; g += 256) {
        const int it = g / 15, c = g - it * 15;
        s4[(it << 4) + (c ^ (it & 15))] = Ag[g];
    }
    __syncthreads();
    float2 av[15];
    if (act) {
        #pragma unroll
        for (int j = 0; j < 15; ++j) {
            const int s = 15 * h + j;          // 8B slot within item row
            const int c = s >> 1, r = s & 1;
            av[j] = s2[(i << 5) + (((c ^ (i & 15)) << 1) | r)];
        }
    }
    __syncthreads();

    // ---- B: stage swizzled + read ----
    const float4* Bg = reinterpret_cast<const float4*>(B) + (size_t)base * 15;
    for (int g = tid; g < n4; g += 256) {
        const int it = g / 15, c = g - it * 15;
        s4[(it << 4) + (c ^ (it & 15))] = Bg[g];
    }
    __syncthreads();
    float2 bv[15];
    if (act) {
        #pragma unroll
        for (int j = 0; j < 15; ++j) {
            const int s = 15 * h + j;
            const int c = s >> 1, r = s & 1;
            bv[j] = s2[(i << 5) + (((c ^ (i & 15)) << 1) | r)];
        }
    }

    // ---- accumulate 10 points (verified round-4/7 math) ----
    float S[16];
    #pragma unroll
    for (int k = 0; k < 16; ++k) S[k] = 0.f;
    if (act) {
        #pragma unroll
        for (int g = 0; g < 5; ++g) {
            float2 a0 = av[3*g+0], a1 = av[3*g+1], a2 = av[3*g+2];
            float2 b0 = bv[3*g+0], b1 = bv[3*g+1], b2 = bv[3*g+2];
            float w0 = wv[2*g]   < 0.f ? 0.f : wv[2*g];
            float w1 = wv[2*g+1] < 0.f ? 0.f : wv[2*g+1];
            {   // point 0: (a0.x, a0.y, a1.x)
                float ax=a0.x, ay=a0.y, az=a1.x;
                float bx=b0.x, by=b0.y, bz=b1.x;
                S[0] += w0;
                float wax=w0*ax, way=w0*ay, waz=w0*az;
                S[1]+=wax; S[2]+=way; S[3]+=waz;
                S[4]+=w0*bx; S[5]+=w0*by; S[6]+=w0*bz;
                S[7] +=wax*bx; S[8] +=wax*by; S[9] +=wax*bz;
                S[10]+=way*bx; S[11]+=way*by; S[12]+=way*bz;
                S[13]+=waz*bx; S[14]+=waz*by; S[15]+=waz*bz;
            }
            {   // point 1: (a1.y, a2.x, a2.y)
                float ax=a1.y, ay=a2.x, az=a2.y;
                float bx=b1.y, by=b2.x, bz=b2.y;
                S[0] += w1;
                float wax=w1*ax, way=w1*ay, waz=w1*az;
                S[1]+=wax; S[2]+=way; S[3]+=waz;
                S[4]+=w1*bx; S[5]+=w1*by; S[6]+=w1*bz;
                S[7] +=wax*bx; S[8] +=wax*by; S[9] +=wax*bz;
                S[10]+=way*bx; S[11]+=way*by; S[12]+=way*bz;
                S[13]+=waz*bx; S[14]+=waz*by; S[15]+=waz*bz;
            }
        }
    }

    // ---- pair combine (lanes 2i <-> 2i+1) ----
    #pragma unroll
    for (int k = 0; k < 16; ++k) S[k] += __shfl_xor(S[k], 1);

    __syncthreads();                      // sbuf's B contents consumed
    if (h == 0 && act) {
        #pragma unroll
        for (int k = 0; k < 16; ++k) sbuf[17 * i + k] = S[k];
    }
    __syncthreads();

    // ---- solve on threads 0..127 (waves 2,3 retire) ----
    if (tid < itemcnt) {
        float Ss[16];
        #pragma unroll
        for (int k = 0; k < 16; ++k) Ss[k] = sbuf[17 * tid + k];
        float R[9], t[3];
        solve16(Ss, R, t);
        float4* O4 = reinterpret_cast<float4*>(Out + (size_t)(base + tid) * 16);
        O4[0] = make_float4(R[0], R[1], R[2], t[0]);
        O4[1] = make_float4(R[3], R[4], R[5], t[1]);
        O4[2] = make_float4(R[6], R[7], R[8], t[2]);
        O4[3] = make_float4(0.f, 0.f, 0.f, 1.f);
    }
}

// ---------------------------------------------------------------------------
// Generic fallback (any n): 1 thread per item, scalar loads.
// ---------------------------------------------------------------------------
__global__ __launch_bounds__(256) void kabsch_generic_kernel(
    const float* __restrict__ A, const float* __restrict__ B,
    const float* __restrict__ W, float* __restrict__ Out,
    int bs, int n)
{
    const int b = blockIdx.x * blockDim.x + threadIdx.x;
    if (b >= bs) return;

    float S[16];
    #pragma unroll
    for (int k = 0; k < 16; ++k) S[k] = 0.f;

    for (int j = 0; j < n; ++j) {
        const float* ap = A + ((size_t)b * n + j) * 3;
        const float* bp = B + ((size_t)b * n + j) * 3;
        float w = W[(size_t)b * n + j];
        w = w < 0.f ? 0.f : w;
        float ax=ap[0], ay=ap[1], az=ap[2];
        float bx=bp[0], by=bp[1], bz=bp[2];
        S[0] += w;
        float wax = w*ax, way = w*ay, waz = w*az;
        S[1] += wax; S[2] += way; S[3] += waz;
        S[4] += w*bx; S[5] += w*by; S[6] += w*bz;
        S[7] += wax*bx; S[8]  += wax*by; S[9]  += wax*bz;
        S[10]+= way*bx; S[11] += way*by; S[12] += way*bz;
        S[13]+= waz*bx; S[14] += waz*by; S[15] += waz*bz;
    }

    float R[9], t[3];
    solve16(S, R, t);

    float4* O4 = reinterpret_cast<float4*>(Out + (size_t)b * 16);
    O4[0] = make_float4(R[0], R[1], R[2], t[0]);
    O4[1] = make_float4(R[3], R[4], R[5], t[1]);
    O4[2] = make_float4(R[6], R[7], R[8], t[2]);
    O4[3] = make_float4(0.f, 0.f, 0.f, 1.f);
}

extern "C" void kernel_launch(void* const* d_in, const int* in_sizes, int n_in,
                              void* d_out, int out_size, void* d_ws, size_t ws_size,
                              hipStream_t stream) {
    const float* A = (const float*)d_in[0];
    const float* B = (const float*)d_in[1];
    const float* W = (const float*)d_in[2];
    float* Out = (float*)d_out;
    const int bs = out_size / 16;
    const int n  = (bs > 0) ? (in_sizes[2] / bs) : 0;
    if (n == 20) {
        const int blocks = (bs + IPB - 1) / IPB;
        hipLaunchKernelGGL(kabsch_swz20_kernel, dim3(blocks), dim3(256), 0, stream,
                           A, B, W, Out, bs);
    } else {
        const int blocks = (bs + 255) / 256;
        hipLaunchKernelGGL(kabsch_generic_kernel, dim3(blocks), dim3(256), 0, stream,
                           A, B, W, Out, bs, n);
    }
}

// Round 10
// 150.104 us; speedup vs baseline: 1.1118x; 1.1118x over previous
//
#include <hip/hip_runtime.h>

#define EPS_W 1e-6f

__device__ __forceinline__ float fast_rsq(float x) { return __builtin_amdgcn_rsqf(x); }
__device__ __forceinline__ float fast_rcp(float x) { return __builtin_amdgcn_rcpf(x); }

// ---------------------------------------------------------------------------
// Horn-quaternion solve via 5-sweep cyclic Jacobi on N (4x4).
// IDENTICAL to rounds 7/8/9 verified version (absmax 0.0039).
// S[16] = { sw, Sa0..2, Sb0..2, M00,M01,M02,M10,M11,M12,M20,M21,M22 }
// ---------------------------------------------------------------------------
__device__ __forceinline__ void solve16(const float S[16], float R[9], float t[3])
{
    const float sw  = S[0];
    const float Sa0 = S[1], Sa1 = S[2], Sa2 = S[3];
    const float Sb0 = S[4], Sb1 = S[5], Sb2 = S[6];

    const float inv = fast_rcp(sw + EPS_W);
    const float cA0 = Sa0*inv, cA1 = Sa1*inv, cA2 = Sa2*inv;
    const float cB0 = Sb0*inv, cB1 = Sb1*inv, cB2 = Sb2*inv;

    float H[3][3];
    H[0][0] = S[7]  - cA0*Sb0 - Sa0*cB0 + sw*cA0*cB0;
    H[0][1] = S[8]  - cA0*Sb1 - Sa0*cB1 + sw*cA0*cB1;
    H[0][2] = S[9]  - cA0*Sb2 - Sa0*cB2 + sw*cA0*cB2;
    H[1][0] = S[10] - cA1*Sb0 - Sa1*cB0 + sw*cA1*cB0;
    H[1][1] = S[11] - cA1*Sb1 - Sa1*cB1 + sw*cA1*cB1;
    H[1][2] = S[12] - cA1*Sb2 - Sa1*cB2 + sw*cA1*cB2;
    H[2][0] = S[13] - cA2*Sb0 - Sa2*cB0 + sw*cA2*cB0;
    H[2][1] = S[14] - cA2*Sb1 - Sa2*cB1 + sw*cA2*cB1;
    H[2][2] = S[15] - cA2*Sb2 - Sa2*cB2 + sw*cA2*cB2;

    const float Sxx=H[0][0], Sxy=H[0][1], Sxz=H[0][2];
    const float Syx=H[1][0], Syy=H[1][1], Syz=H[1][2];
    const float Szx=H[2][0], Szy=H[2][1], Szz=H[2][2];

    float Nm[4][4];
    Nm[0][0] =  Sxx+Syy+Szz; Nm[0][1] = Syz-Szy;      Nm[0][2] = Szx-Sxz;      Nm[0][3] = Sxy-Syx;
    Nm[1][0] =  Nm[0][1];    Nm[1][1] = Sxx-Syy-Szz;  Nm[1][2] = Sxy+Syx;      Nm[1][3] = Szx+Sxz;
    Nm[2][0] =  Nm[0][2];    Nm[2][1] = Nm[1][2];     Nm[2][2] = -Sxx+Syy-Szz; Nm[2][3] = Syz+Szy;
    Nm[3][0] =  Nm[0][3];    Nm[3][1] = Nm[1][3];     Nm[3][2] = Nm[2][3];     Nm[3][3] = -Sxx-Syy+Szz;

    float Vv[4][4] = {{1.f,0.f,0.f,0.f},{0.f,1.f,0.f,0.f},{0.f,0.f,1.f,0.f},{0.f,0.f,0.f,1.f}};

    for (int sweep = 0; sweep < 5; ++sweep) {
        #pragma unroll
        for (int pair = 0; pair < 6; ++pair) {
            constexpr int PP[6] = {0,0,0,1,1,2};
            constexpr int QQ[6] = {1,2,3,2,3,3};
            const int p = PP[pair], q = QQ[pair];
            float d  = Nm[p][p] - Nm[q][q];
            float o  = Nm[p][q];
            float r2 = d*d + 4.f*o*o;
            bool tiny = r2 < 1e-30f;
            float rinv = fast_rsq(tiny ? 1.f : r2);
            float hh = 0.5f + 0.5f * fabsf(d) * rinv;
            float ci = fast_rsq(hh);
            float c  = hh * ci;
            float s  = (d < 0.f ? o : -o) * rinv * ci;
            c = tiny ? 1.f : c;
            s = tiny ? 0.f : s;
            #pragma unroll
            for (int k = 0; k < 4; ++k) {
                float akp = Nm[k][p], akq = Nm[k][q];
                Nm[k][p] = c*akp - s*akq;
                Nm[k][q] = s*akp + c*akq;
            }
            #pragma unroll
            for (int k = 0; k < 4; ++k) {
                float apk = Nm[p][k], aqk = Nm[q][k];
                Nm[p][k] = c*apk - s*aqk;
                Nm[q][k] = s*apk + c*aqk;
            }
            #pragma unroll
            for (int k = 0; k < 4; ++k) {
                float vkp = Vv[k][p], vkq = Vv[k][q];
                Vv[k][p] = c*vkp - s*vkq;
                Vv[k][q] = s*vkp + c*vkq;
            }
        }
    }

    float q0=Vv[0][0], q1=Vv[1][0], q2=Vv[2][0], q3=Vv[3][0];
    float best = Nm[0][0];
    #pragma unroll
    for (int m = 1; m < 4; ++m) {
        bool bt = Nm[m][m] > best;
        best = bt ? Nm[m][m] : best;
        q0 = bt ? Vv[0][m] : q0;
        q1 = bt ? Vv[1][m] : q1;
        q2 = bt ? Vv[2][m] : q2;
        q3 = bt ? Vv[3][m] : q3;
    }
    float qn = fast_rsq(q0*q0 + q1*q1 + q2*q2 + q3*q3);
    q0*=qn; q1*=qn; q2*=qn; q3*=qn;

    float R00 = q0*q0+q1*q1-q2*q2-q3*q3;
    float R01 = 2.f*(q1*q2 - q0*q3);
    float R02 = 2.f*(q1*q3 + q0*q2);
    float R10 = 2.f*(q1*q2 + q0*q3);
    float R11 = q0*q0-q1*q1+q2*q2-q3*q3;
    float R12 = 2.f*(q2*q3 - q0*q1);
    float R20 = 2.f*(q1*q3 - q0*q2);
    float R21 = 2.f*(q2*q3 + q0*q1);
    float R22 = q0*q0-q1*q1-q2*q2+q3*q3;

    float trRH  = R00*Sxx+R01*Syx+R02*Szx
                + R10*Sxy+R11*Syy+R12*Szy
                + R20*Sxz+R21*Syz+R22*Szz;
    float trRtH = R00*Sxx+R01*Sxy+R02*Sxz
                + R10*Syx+R11*Syy+R12*Syz
                + R20*Szx+R21*Szy+R22*Szz;
    if (trRtH > trRH) {
        float tt;
        tt = R01; R01 = R10; R10 = tt;
        tt = R02; R02 = R20; R20 = tt;
        tt = R12; R12 = R21; R21 = tt;
    }

    R[0]=R00; R[1]=R01; R[2]=R02;
    R[3]=R10; R[4]=R11; R[5]=R12;
    R[6]=R20; R[7]=R21; R[8]=R22;
    t[0] = cB0 - (R00*cA0 + R01*cA1 + R02*cA2);
    t[1] = cB1 - (R10*cA0 + R11*cA1 + R12*cA2);
    t[2] = cB2 - (R20*cA0 + R21*cA1 + R22*cA2);
}

// ---------------------------------------------------------------------------
// v10: 1-wave blocks (64 threads), 64 items/block, NO barriers.
//  - two accumulate passes of 32 items (2 lanes/item, round-4/7-verified
//    float2 loads), pair-combine via shfl_xor, even lane stashes 16 sums in
//    LDS (stride 17 -> 2 lanes/bank, free). Same-wave LDS => no syncthreads.
//  - then ALL 64 lanes solve one item each (no idle lanes, no redundancy).
//  - outputs restaged through LDS -> 4 coalesced float4 stores per lane.
//  - 3125 blocks (=12.2/CU), LDS 4.4KB, VGPR<=128 (launch_bounds(64,4))
//    => ~16 resident 1-wave blocks/CU: latency hidden by independent waves.
// ---------------------------------------------------------------------------
__global__ __launch_bounds__(64, 4) void kabsch_wave20_kernel(
    const float* __restrict__ A, const float* __restrict__ B,
    const float* __restrict__ W, float* __restrict__ Out, int bs)
{
    __shared__ float sums[64 * 17];        // 4352 B per 1-wave block

    const int lane = threadIdx.x;          // 0..63
    const int base = blockIdx.x * 64;
    const int i = lane >> 1;               // item-in-group, 0..31
    const int h = lane & 1;                // half: points 0..9 / 10..19

    const float2* A2 = reinterpret_cast<const float2*>(A);
    const float2* B2 = reinterpret_cast<const float2*>(B);
    const float2* W2 = reinterpret_cast<const float2*>(W);

    #pragma unroll
    for (int grp = 0; grp < 2; ++grp) {
        int item  = base + grp * 32 + i;
        int itemc = item < bs ? item : bs - 1;     // clamp loads
        const int abase = itemc * 30 + h * 15;
        const int wbase = itemc * 10 + h * 5;

        // load the half-item upfront: 35 independent float2 loads in flight
        float2 av[15], bv[15], wv2[5];
        #pragma unroll
        for (int j = 0; j < 15; ++j) av[j] = A2[abase + j];
        #pragma unroll
        for (int j = 0; j < 15; ++j) bv[j] = B2[abase + j];
        #pragma unroll
        for (int j = 0; j < 5;  ++j) wv2[j] = W2[wbase + j];

        float S[16];
        #pragma unroll
        for (int k = 0; k < 16; ++k) S[k] = 0.f;

        #pragma unroll
        for (int g = 0; g < 5; ++g) {
            float2 a0 = av[3*g+0], a1 = av[3*g+1], a2 = av[3*g+2];
            float2 b0 = bv[3*g+0], b1 = bv[3*g+1], b2 = bv[3*g+2];
            float w0 = wv2[g].x < 0.f ? 0.f : wv2[g].x;
            float w1 = wv2[g].y < 0.f ? 0.f : wv2[g].y;
            {   // point 0: (a0.x, a0.y, a1.x)
                float ax=a0.x, ay=a0.y, az=a1.x;
                float bx=b0.x, by=b0.y, bz=b1.x;
                S[0] += w0;
                float wax=w0*ax, way=w0*ay, waz=w0*az;
                S[1]+=wax; S[2]+=way; S[3]+=waz;
                S[4]+=w0*bx; S[5]+=w0*by; S[6]+=w0*bz;
                S[7] +=wax*bx; S[8] +=wax*by; S[9] +=wax*bz;
                S[10]+=way*bx; S[11]+=way*by; S[12]+=way*bz;
                S[13]+=waz*bx; S[14]+=waz*by; S[15]+=waz*bz;
            }
            {   // point 1: (a1.y, a2.x, a2.y)
                float ax=a1.y, ay=a2.x, az=a2.y;
                float bx=b1.y, by=b2.x, bz=b2.y;
                S[0] += w1;
                float wax=w1*ax, way=w1*ay, waz=w1*az;
                S[1]+=wax; S[2]+=way; S[3]+=waz;
                S[4]+=w1*bx; S[5]+=w1*by; S[6]+=w1*bz;
                S[7] +=wax*bx; S[8] +=wax*by; S[9] +=wax*bz;
                S[10]+=way*bx; S[11]+=way*by; S[12]+=way*bz;
                S[13]+=waz*bx; S[14]+=waz*by; S[15]+=waz*bz;
            }
        }

        // pair combine (lanes 2i <-> 2i+1)
        #pragma unroll
        for (int k = 0; k < 16; ++k) S[k] += __shfl_xor(S[k], 1);

        // even lane stashes the item's sums (same-wave LDS, no barrier)
        if (h == 0) {
            const int row = grp * 32 + i;
            #pragma unroll
            for (int k = 0; k < 16; ++k) sums[row * 17 + k] = S[k];
        }
    }

    // ---- every lane solves one item (lockstep wave => stash complete) ----
    float Ss[16];
    #pragma unroll
    for (int k = 0; k < 16; ++k) Ss[k] = sums[lane * 17 + k];

    float R[9], t[3];
    solve16(Ss, R, t);

    // restage output in LDS (reuse sums; wave lockstep => reads done)
    {
        float* o = &sums[lane * 17];
        o[0]=R[0];  o[1]=R[1];  o[2]=R[2];  o[3]=t[0];
        o[4]=R[3];  o[5]=R[4];  o[6]=R[5];  o[7]=t[1];
        o[8]=R[6];  o[9]=R[7];  o[10]=R[8]; o[11]=t[2];
        o[12]=0.f;  o[13]=0.f;  o[14]=0.f;  o[15]=1.f;
    }

    // coalesced output: 4 float4 per lane
    float4* Og = reinterpret_cast<float4*>(Out) + (size_t)base * 4;
    #pragma unroll
    for (int j2 = 0; j2 < 4; ++j2) {
        const int j  = j2 * 64 + lane;     // float4 index within block
        const int it = j >> 2;
        if (base + it < bs) {
            const float* o = &sums[it * 17 + (j & 3) * 4];
            Og[j] = make_float4(o[0], o[1], o[2], o[3]);
        }
    }
}

// ---------------------------------------------------------------------------
// Generic fallback (any n): 1 thread per item, scalar loads.
// ---------------------------------------------------------------------------
__global__ __launch_bounds__(256) void kabsch_generic_kernel(
    const float* __restrict__ A, const float* __restrict__ B,
    const float* __restrict__ W, float* __restrict__ Out,
    int bs, int n)
{
    const int b = blockIdx.x * blockDim.x + threadIdx.x;
    if (b >= bs) return;

    float S[16];
    #pragma unroll
    for (int k = 0; k < 16; ++k) S[k] = 0.f;

    for (int j = 0; j < n; ++j) {
        const float* ap = A + ((size_t)b * n + j) * 3;
        const float* bp = B + ((size_t)b * n + j) * 3;
        float w = W[(size_t)b * n + j];
        w = w < 0.f ? 0.f : w;
        float ax=ap[0], ay=ap[1], az=ap[2];
        float bx=bp[0], by=bp[1], bz=bp[2];
        S[0] += w;
        float wax = w*ax, way = w*ay, waz = w*az;
        S[1] += wax; S[2] += way; S[3] += waz;
        S[4] += w*bx; S[5] += w*by; S[6] += w*bz;
        S[7] += wax*bx; S[8]  += wax*by; S[9]  += wax*bz;
        S[10]+= way*bx; S[11] += way*by; S[12] += way*bz;
        S[13]+= waz*bx; S[14] += waz*by; S[15] += waz*bz;
    }

    float R[9], t[3];
    solve16(S, R, t);

    float4* O4 = reinterpret_cast<float4*>(Out + (size_t)b * 16);
    O4[0] = make_float4(R[0], R[1], R[2], t[0]);
    O4[1] = make_float4(R[3], R[4], R[5], t[1]);
    O4[2] = make_float4(R[6], R[7], R[8], t[2]);
    O4[3] = make_float4(0.f, 0.f, 0.f, 1.f);
}

extern "C" void kernel_launch(void* const* d_in, const int* in_sizes, int n_in,
                              void* d_out, int out_size, void* d_ws, size_t ws_size,
                              hipStream_t stream) {
    const float* A = (const float*)d_in[0];
    const float* B = (const float*)d_in[1];
    const float* W = (const float*)d_in[2];
    float* Out = (float*)d_out;
    const int bs = out_size / 16;
    const int n  = (bs > 0) ? (in_sizes[2] / bs) : 0;
    if (n == 20) {
        const int blocks = (bs + 63) / 64;
        hipLaunchKernelGGL(kabsch_wave20_kernel, dim3(blocks), dim3(64), 0, stream,
                           A, B, W, Out, bs);
    } else {
        const int blocks = (bs + 255) / 256;
        hipLaunchKernelGGL(kabsch_generic_kernel, dim3(blocks), dim3(256), 0, stream,
                           A, B, W, Out, bs, n);
    }
}